// Round 6
// baseline (971.751 us; speedup 1.0000x reference)
//
#include <hip/hip_runtime.h>
#include <hip/hip_bf16.h>

#define D_IN 768
#define D_HID 256

typedef __attribute__((ext_vector_type(8))) short short8;
typedef __attribute__((ext_vector_type(4))) float f32x4;
typedef __attribute__((ext_vector_type(4))) unsigned int u32x4;

__device__ inline float b2f(unsigned short u) {
    unsigned x = ((unsigned)u) << 16;
    union { unsigned u; float f; } c; c.u = x; return c.f;
}
__device__ inline unsigned short f2b(float v) {
    __hip_bfloat16 h = __float2bfloat16(v);
    return *(unsigned short*)&h;
}
// truncating bf16 hi (error compensated by lo term)
__device__ inline short trunc_hi(float v) {
    unsigned u = __builtin_bit_cast(unsigned, v);
    return (short)(u >> 16);
}
__device__ inline float hi_f(float v) {
    unsigned u = __builtin_bit_cast(unsigned, v) & 0xffff0000u;
    return __builtin_bit_cast(float, u);
}

// ---------------- CSR build ----------------

__global__ void k_count(const int* __restrict__ dst, int* __restrict__ deg, int E) {
    int i = blockIdx.x * 256 + threadIdx.x;
    if (i < E) atomicAdd(&deg[dst[i]], 1);
}

__global__ void k_dinv(const int* __restrict__ deg, float* __restrict__ dinv, int N) {
    int i = blockIdx.x * 256 + threadIdx.x;
    if (i < N) dinv[i] = rsqrtf((float)deg[i] + 1.0f);
}

__global__ __launch_bounds__(1024) void k_scan(const int* __restrict__ deg,
                                               int* __restrict__ row_ptr, int N) {
    __shared__ int wsum[16];
    __shared__ int carry_s;
    int t = threadIdx.x;
    int lane = t & 63, wid = t >> 6;
    if (t == 0) carry_s = 0;
    __syncthreads();
    for (int base = 0; base < N; base += 1024) {
        int i = base + t;
        int v = (i < N) ? deg[i] : 0;
        int s = v;
        #pragma unroll
        for (int d = 1; d < 64; d <<= 1) {
            int tmp = __shfl_up(s, d);
            if (lane >= d) s += tmp;
        }
        if (lane == 63) wsum[wid] = s;
        __syncthreads();
        if (wid == 0 && lane < 16) {
            int ws = wsum[lane];
            #pragma unroll
            for (int d = 1; d < 16; d <<= 1) {
                int tmp = __shfl_up(ws, d);
                if (lane >= d) ws += tmp;
            }
            wsum[lane] = ws;
        }
        __syncthreads();
        int carry = carry_s;
        int woff = (wid > 0) ? wsum[wid - 1] : 0;
        if (i < N) row_ptr[i] = carry + woff + s - v;
        __syncthreads();
        if (t == 0) carry_s = carry + wsum[15];
        __syncthreads();
    }
    if (t == 0) row_ptr[N] = carry_s;
}

__global__ void k_fill(const int* __restrict__ src, const int* __restrict__ dst,
                       const int* __restrict__ row_ptr, int* __restrict__ wptr,
                       int* __restrict__ csr_src, int E) {
    int i = blockIdx.x * 256 + threadIdx.x;
    if (i < E) {
        int d = dst[i];
        int w = atomicAdd(&wptr[d], 1);
        csr_src[row_ptr[d] + w] = src[i];
    }
}

__global__ void k_bounds(const int* __restrict__ batch, int* __restrict__ cnt,
                         int* __restrict__ offg, int N, int G) {
    int g = threadIdx.x;
    if (g >= G) return;
    auto lower = [&](int key) {
        int lo = 0, hi = N;
        while (lo < hi) {
            int mid = (lo + hi) >> 1;
            if (batch[mid] < key) lo = mid + 1; else hi = mid;
        }
        return lo;
    };
    int lo = lower(g);
    int hi = lower(g + 1);
    offg[g] = lo;
    cnt[g] = hi - lo;
}

// ---------------- B prep: W fp32 [KA][256] -> hi/lo planes, fragment-swizzled ----
// elem offset within plane: ((c*2 + half)*4 + q)*1024 + nn*8 + j
//   k = c*32 + q*8 + j ; n = half*128 + nn
__global__ void k_prep_B2(const float* __restrict__ W, short* __restrict__ Bp, int KA) {
    int t = blockIdx.x * 256 + threadIdx.x;
    if (t >= KA * 256) return;
    int k = t >> 8, n = t & 255;
    float v = W[(size_t)k * 256 + n];
    unsigned short h = f2b(v);
    unsigned short l = f2b(v - b2f(h));
    int c = k >> 5, q = (k >> 3) & 3, j = k & 7;
    int halfn = n >> 7, nn = n & 127;
    size_t off = ((size_t)(c * 2 + halfn) * 4 + q) * 1024 + nn * 8 + j;
    size_t PLANE = (size_t)(KA / 32) * 2 * 4096;
    Bp[off] = (short)h;
    Bp[PLANE + off] = (short)l;
}

// ---------------- barrier-free MFMA GEMM ----------------
// C[M,256] = A[M,KA] @ W[KA,256] via split-bf16 passes.
// MODE 1: A fp32 (layer 1), passes (A_hi*W_hi, A_lo*W_hi, A_hi*W_lo).
// MODE 2: A bf16 exact (layers 2/3), passes (A*W_hi, A*W_lo).
// One wave per block: 64 rows (4 strips of 16) x 128 cols (8 tiles of 16).
template <int MODE>
__global__ __launch_bounds__(64, 2) void k_gemm3(const void* __restrict__ Av,
                                                 const short* __restrict__ Bp,
                                                 unsigned short* __restrict__ C,
                                                 int M) {
    constexpr int KA = (MODE == 1) ? D_IN : D_HID;
    constexpr int NCH = KA / 32;
    constexpr int NPASS = (MODE == 1) ? 3 : 2;
    constexpr int PLANE = NCH * 2 * 4096;
    int lane = threadIdx.x;
    int ln = lane & 15, q = lane >> 4;
    int bm = blockIdx.x * 64;
    int half = blockIdx.y;

    f32x4 acc[4][8];
    #pragma unroll
    for (int s = 0; s < 4; ++s)
        #pragma unroll
        for (int tt = 0; tt < 8; ++tt) acc[s][tt] = (f32x4){0.f, 0.f, 0.f, 0.f};

    int rbase[4]; bool rowok[4];
    #pragma unroll
    for (int s = 0; s < 4; ++s) { rbase[s] = bm + s * 16 + ln; rowok[s] = rbase[s] < M; }

    #pragma unroll
    for (int p = 0; p < NPASS; ++p) {
        const short* Bb = Bp + ((MODE == 1) ? ((p == 2) ? PLANE : 0) : p * PLANE);
        for (int cc = 0; cc < NCH; ++cc) {
            // A fragments (non-temporal: keep L1 for B)
            short8 a[4];
            #pragma unroll
            for (int s = 0; s < 4; ++s) {
                if (MODE == 1) {
                    const float* Af = (const float*)Av + (size_t)rbase[s] * KA + cc * 32 + q * 8;
                    f32x4 v0 = (f32x4){0.f, 0.f, 0.f, 0.f}, v1 = v0;
                    if (rowok[s]) {
                        v0 = __builtin_bit_cast(f32x4, __builtin_nontemporal_load((const u32x4*)Af));
                        v1 = __builtin_bit_cast(f32x4, __builtin_nontemporal_load((const u32x4*)(Af + 4)));
                    }
                    float vv[8] = {v0[0], v0[1], v0[2], v0[3], v1[0], v1[1], v1[2], v1[3]};
                    #pragma unroll
                    for (int j = 0; j < 8; ++j)
                        a[s][j] = (p == 1) ? (short)f2b(vv[j] - hi_f(vv[j])) : trunc_hi(vv[j]);
                } else {
                    const unsigned short* Ab =
                        (const unsigned short*)Av + (size_t)rbase[s] * KA + cc * 32 + q * 8;
                    short8 av = (short8){0, 0, 0, 0, 0, 0, 0, 0};
                    if (rowok[s])
                        av = __builtin_bit_cast(short8, __builtin_nontemporal_load((const u32x4*)Ab));
                    a[s] = av;
                }
            }
            // B fragments: coalesced, L1-shared across waves
            const short* bb = Bb + (size_t)(cc * 2 + half) * 4096 + q * 1024 + ln * 8;
            short8 b[8];
            #pragma unroll
            for (int tt = 0; tt < 8; ++tt) b[tt] = *(const short8*)(bb + tt * 128);
            #pragma unroll
            for (int tt = 0; tt < 8; ++tt)
                #pragma unroll
                for (int s = 0; s < 4; ++s)
                    acc[s][tt] = __builtin_amdgcn_mfma_f32_16x16x32_bf16(a[s], b[tt], acc[s][tt], 0, 0, 0);
        }
    }
    // C/D: col = half*128 + tt*16 + ln, row = bm + s*16 + q*4 + r
    #pragma unroll
    for (int s = 0; s < 4; ++s)
        #pragma unroll
        for (int tt = 0; tt < 8; ++tt)
            #pragma unroll
            for (int r = 0; r < 4; ++r) {
                int row = bm + s * 16 + q * 4 + r;
                if (row < M)
                    C[(size_t)row * 256 + half * 128 + tt * 16 + ln] = f2b(acc[s][tt][r]);
            }
}

// ---------------- aggregation: one wave per dst row, bf16 gather ----------------
template <int RELU, int OUTBF>
__global__ __launch_bounds__(256) void k_agg(const unsigned short* __restrict__ hin,
                                             void* __restrict__ hout,
                                             const int* __restrict__ row_ptr,
                                             const int* __restrict__ csr_src,
                                             const float* __restrict__ dinv,
                                             const float* __restrict__ bias, int N) {
    int w = threadIdx.x >> 6;
    int lane = threadIdx.x & 63;
    int row = blockIdx.x * 4 + w;
    if (row >= N) return;
    int c4 = lane * 4;
    int s = row_ptr[row], e = row_ptr[row + 1];
    float a0 = 0.f, a1 = 0.f, a2 = 0.f, a3 = 0.f;
    int j = s;
    for (; j + 4 <= e; j += 4) {
        int u0 = csr_src[j], u1 = csr_src[j + 1], u2 = csr_src[j + 2], u3 = csr_src[j + 3];
        float d0 = dinv[u0], d1 = dinv[u1], d2 = dinv[u2], d3 = dinv[u3];
        ushort4 v0 = *(const ushort4*)&hin[(size_t)u0 * 256 + c4];
        ushort4 v1 = *(const ushort4*)&hin[(size_t)u1 * 256 + c4];
        ushort4 v2 = *(const ushort4*)&hin[(size_t)u2 * 256 + c4];
        ushort4 v3 = *(const ushort4*)&hin[(size_t)u3 * 256 + c4];
        a0 += d0 * b2f(v0.x) + d1 * b2f(v1.x) + d2 * b2f(v2.x) + d3 * b2f(v3.x);
        a1 += d0 * b2f(v0.y) + d1 * b2f(v1.y) + d2 * b2f(v2.y) + d3 * b2f(v3.y);
        a2 += d0 * b2f(v0.z) + d1 * b2f(v1.z) + d2 * b2f(v2.z) + d3 * b2f(v3.z);
        a3 += d0 * b2f(v0.w) + d1 * b2f(v1.w) + d2 * b2f(v2.w) + d3 * b2f(v3.w);
    }
    for (; j < e; ++j) {
        int u = csr_src[j];
        float d = dinv[u];
        ushort4 v = *(const ushort4*)&hin[(size_t)u * 256 + c4];
        a0 += d * b2f(v.x); a1 += d * b2f(v.y); a2 += d * b2f(v.z); a3 += d * b2f(v.w);
    }
    float di = dinv[row];
    float dii = di * di;
    ushort4 vs = *(const ushort4*)&hin[(size_t)row * 256 + c4];
    float4 bb = *(const float4*)&bias[c4];
    a0 = a0 * di + dii * b2f(vs.x) + bb.x;
    a1 = a1 * di + dii * b2f(vs.y) + bb.y;
    a2 = a2 * di + dii * b2f(vs.z) + bb.z;
    a3 = a3 * di + dii * b2f(vs.w) + bb.w;
    if (RELU) {
        a0 = fmaxf(a0, 0.f); a1 = fmaxf(a1, 0.f);
        a2 = fmaxf(a2, 0.f); a3 = fmaxf(a3, 0.f);
    }
    if (OUTBF) {
        ushort4 o; o.x = f2b(a0); o.y = f2b(a1); o.z = f2b(a2); o.w = f2b(a3);
        *(ushort4*)((unsigned short*)hout + (size_t)row * 256 + c4) = o;
    } else {
        *(float4*)((float*)hout + (size_t)row * 256 + c4) = make_float4(a0, a1, a2, a3);
    }
}

// ---------------- pool ----------------
__global__ __launch_bounds__(256) void k_pool(const float* __restrict__ h,
                                              const int* __restrict__ cnt,
                                              const int* __restrict__ offg,
                                              float* __restrict__ g) {
    int gi = blockIdx.x, slice = blockIdx.y;
    int c = threadIdx.x;
    int start = offg[gi], n = cnt[gi];
    int per = (n + (int)gridDim.y - 1) / (int)gridDim.y;
    int r0 = slice * per;
    int r1 = min(n, r0 + per);
    float acc = 0.f;
    for (int r = r0; r < r1; ++r) acc += h[(size_t)(start + r) * D_HID + c];
    if (r1 > r0) atomicAdd(&g[gi * D_HID + c], acc);
}

// ---------------- head ----------------
__global__ __launch_bounds__(256) void k_final(const float* __restrict__ g,
                                               const int* __restrict__ cnt,
                                               const float* __restrict__ Wl,
                                               const float* __restrict__ bl,
                                               float* __restrict__ out) {
    __shared__ float gs[D_HID];
    int t = threadIdx.x;
    int gi = blockIdx.y;
    int c = blockIdx.x * 256 + t;
    float inv = 1.0f / (float)max(cnt[gi], 1);
    gs[t] = g[gi * D_HID + t] * inv;
    __syncthreads();
    float acc = bl[c];
    #pragma unroll 8
    for (int k = 0; k < D_HID; ++k) acc = fmaf(gs[k], Wl[(size_t)k * D_IN + c], acc);
    out[(size_t)gi * D_IN + c] = acc;
}

// ---------------- launch ----------------

extern "C" void kernel_launch(void* const* d_in, const int* in_sizes, int n_in,
                              void* d_out, int out_size, void* d_ws, size_t ws_size,
                              hipStream_t stream) {
    const float* x     = (const float*)d_in[0];
    const int*   ei    = (const int*)d_in[1];
    const int*   batch = (const int*)d_in[2];
    const float* W1 = (const float*)d_in[3];
    const float* b1 = (const float*)d_in[4];
    const float* W2 = (const float*)d_in[5];
    const float* b2 = (const float*)d_in[6];
    const float* W3 = (const float*)d_in[7];
    const float* b3 = (const float*)d_in[8];
    const float* Wl = (const float*)d_in[9];
    const float* bl = (const float*)d_in[10];
    float* out = (float*)d_out;

    int N = in_sizes[2];
    int E = in_sizes[1] / 2;
    int G = out_size / D_IN;
    const int* srcp = ei;
    const int* dstp = ei + E;

    char* ws = (char*)d_ws;
    size_t o = 0;
    auto alloc = [&](size_t bytes) -> char* {
        char* p = ws + o;
        o += (bytes + 255) & ~(size_t)255;
        return p;
    };
    int*   deg     = (int*)alloc((size_t)N * 4);
    int*   wptr    = (int*)alloc((size_t)N * 4);
    int*   row_ptr = (int*)alloc((size_t)(N + 1) * 4);
    int*   cnt     = (int*)alloc((size_t)G * 4);
    int*   offg    = (int*)alloc((size_t)G * 4);
    int*   csr_src = (int*)alloc((size_t)E * 4);
    float* dinv    = (float*)alloc((size_t)N * 4);
    float* gbuf    = (float*)alloc((size_t)G * D_HID * 4);
    unsigned short* hG  = (unsigned short*)alloc((size_t)N * D_HID * 2); // GEMM out (bf16)
    unsigned short* hA2 = (unsigned short*)alloc((size_t)N * D_HID * 2); // agg out L1/L2 (bf16)
    float* hF      = (float*)alloc((size_t)N * D_HID * 4);               // agg out L3 (fp32)
    short* Bp1     = (short*)alloc((size_t)(D_IN / 32) * 2 * 4096 * 2 * 2);  // hi+lo planes
    short* Bp2     = (short*)alloc((size_t)(D_HID / 32) * 2 * 4096 * 2 * 2);
    short* Bp3     = (short*)alloc((size_t)(D_HID / 32) * 2 * 4096 * 2 * 2);

    hipMemsetAsync(deg, 0, (size_t)N * 4, stream);
    hipMemsetAsync(wptr, 0, (size_t)N * 4, stream);
    hipMemsetAsync(gbuf, 0, (size_t)G * D_HID * 4, stream);

    int gE = (E + 255) / 256;
    int gN = (N + 255) / 256;

    k_count<<<gE, 256, 0, stream>>>(dstp, deg, E);
    k_dinv<<<gN, 256, 0, stream>>>(deg, dinv, N);
    k_scan<<<1, 1024, 0, stream>>>(deg, row_ptr, N);
    k_fill<<<gE, 256, 0, stream>>>(srcp, dstp, row_ptr, wptr, csr_src, E);
    k_bounds<<<1, 64, 0, stream>>>(batch, cnt, offg, N, G);

    k_prep_B2<<<D_IN, 256, 0, stream>>>(W1, Bp1, D_IN);
    k_prep_B2<<<D_HID, 256, 0, stream>>>(W2, Bp2, D_HID);
    k_prep_B2<<<D_HID, 256, 0, stream>>>(W3, Bp3, D_HID);

    dim3 gemm_grid((N + 63) / 64, 2);
    int agg_grid = (N + 3) / 4;

    // layer 1 (fp32 A, 3-pass split)
    k_gemm3<1><<<gemm_grid, 64, 0, stream>>>(x, Bp1, hG, N);
    k_agg<1, 1><<<agg_grid, 256, 0, stream>>>(hG, hA2, row_ptr, csr_src, dinv, b1, N);
    // layer 2 (bf16 A exact, 2-pass)
    k_gemm3<2><<<gemm_grid, 64, 0, stream>>>(hA2, Bp2, hG, N);
    k_agg<1, 1><<<agg_grid, 256, 0, stream>>>(hG, hA2, row_ptr, csr_src, dinv, b2, N);
    // layer 3
    k_gemm3<2><<<gemm_grid, 64, 0, stream>>>(hA2, Bp3, hG, N);
    k_agg<0, 0><<<agg_grid, 256, 0, stream>>>(hG, hF, row_ptr, csr_src, dinv, b3, N);

    // pool + head
    dim3 pool_grid(G, 8);
    k_pool<<<pool_grid, 256, 0, stream>>>(hF, cnt, offg, gbuf);
    dim3 fin_grid(D_IN / 256, G);
    k_final<<<fin_grid, 256, 0, stream>>>(gbuf, cnt, Wl, bl, out);
}

// Round 7
// 789.129 us; speedup vs baseline: 1.2314x; 1.2314x over previous
//
#include <hip/hip_runtime.h>
#include <hip/hip_bf16.h>

#define D_IN 768
#define D_HID 256

typedef __attribute__((ext_vector_type(8))) short short8;
typedef __attribute__((ext_vector_type(4))) float f32x4;

__device__ inline float b2f(unsigned short u) {
    unsigned x = ((unsigned)u) << 16;
    union { unsigned u; float f; } c; c.u = x; return c.f;
}
__device__ inline unsigned short f2b(float v) {
    __hip_bfloat16 h = __float2bfloat16(v);
    return *(unsigned short*)&h;
}

__device__ inline void gload_lds16(const void* g, void* l) {
    __builtin_amdgcn_global_load_lds(
        (const __attribute__((address_space(1))) unsigned int*)g,
        (__attribute__((address_space(3))) unsigned int*)l, 16, 0, 0);
}

// ---------------- CSR build ----------------

__global__ void k_count(const int* __restrict__ dst, int* __restrict__ deg, int E) {
    int i = blockIdx.x * 256 + threadIdx.x;
    if (i < E) atomicAdd(&deg[dst[i]], 1);
}

__global__ void k_dinv(const int* __restrict__ deg, float* __restrict__ dinv, int N) {
    int i = blockIdx.x * 256 + threadIdx.x;
    if (i < N) dinv[i] = rsqrtf((float)deg[i] + 1.0f);
}

__global__ __launch_bounds__(1024) void k_scan(const int* __restrict__ deg,
                                               int* __restrict__ row_ptr, int N) {
    __shared__ int wsum[16];
    __shared__ int carry_s;
    int t = threadIdx.x;
    int lane = t & 63, wid = t >> 6;
    if (t == 0) carry_s = 0;
    __syncthreads();
    for (int base = 0; base < N; base += 1024) {
        int i = base + t;
        int v = (i < N) ? deg[i] : 0;
        int s = v;
        #pragma unroll
        for (int d = 1; d < 64; d <<= 1) {
            int tmp = __shfl_up(s, d);
            if (lane >= d) s += tmp;
        }
        if (lane == 63) wsum[wid] = s;
        __syncthreads();
        if (wid == 0 && lane < 16) {
            int ws = wsum[lane];
            #pragma unroll
            for (int d = 1; d < 16; d <<= 1) {
                int tmp = __shfl_up(ws, d);
                if (lane >= d) ws += tmp;
            }
            wsum[lane] = ws;
        }
        __syncthreads();
        int carry = carry_s;
        int woff = (wid > 0) ? wsum[wid - 1] : 0;
        if (i < N) row_ptr[i] = carry + woff + s - v;
        __syncthreads();
        if (t == 0) carry_s = carry + wsum[15];
        __syncthreads();
    }
    if (t == 0) row_ptr[N] = carry_s;
}

__global__ void k_fill(const int* __restrict__ src, const int* __restrict__ dst,
                       const int* __restrict__ row_ptr, int* __restrict__ wptr,
                       int* __restrict__ csr_src, int E) {
    int i = blockIdx.x * 256 + threadIdx.x;
    if (i < E) {
        int d = dst[i];
        int w = atomicAdd(&wptr[d], 1);
        csr_src[row_ptr[d] + w] = src[i];
    }
}

__global__ void k_bounds(const int* __restrict__ batch, int* __restrict__ cnt,
                         int* __restrict__ offg, int N, int G) {
    int g = threadIdx.x;
    if (g >= G) return;
    auto lower = [&](int key) {
        int lo = 0, hi = N;
        while (lo < hi) {
            int mid = (lo + hi) >> 1;
            if (batch[mid] < key) lo = mid + 1; else hi = mid;
        }
        return lo;
    };
    int lo = lower(g);
    int hi = lower(g + 1);
    offg[g] = lo;
    cnt[g] = hi - lo;
}

// ---------------- B prep: W fp32 [KA][256] -> per-chunk fragment-swizzled hi/lo --
// chunk c (32 k's) = 16384 shorts:
//   off = c*16384 + (((f*16 + tile)*4 + q)*16 + ln)*8 + j
//   k = c*32 + q*8 + j ; n = tile*16 + ln ; f: 0=hi,1=lo
__global__ void k_prep_B(const float* __restrict__ W, short* __restrict__ Bp, int KA) {
    int t = blockIdx.x * 256 + threadIdx.x;
    if (t >= KA * 256) return;
    int k = t >> 8, n = t & 255;
    float v = W[(size_t)k * 256 + n];
    unsigned short h = f2b(v);
    unsigned short l = f2b(v - b2f(h));
    int c = k >> 5, q = (k >> 3) & 3, j = k & 7;
    int tile = n >> 4, ln = n & 15;
    size_t base = (size_t)c * 16384 + (size_t)(tile * 4 + q) * 128 + ln * 8 + j;
    Bp[base] = (short)h;            // f=0
    Bp[base + 8192] = (short)l;     // f=1 (16*4*128 = 8192)
}

// ---------------- MFMA GEMM: C[M,256] = A[M,KA] @ W, fused split-bf16 ----------
// 256 thr = 4 waves; wave w: 64 rows x cols [w*64, w*64+64). BK=32, dbuf LDS.
// MODE 1: A fp32, 3 terms (ah*bh, al*bh, ah*bl). MODE 2: A bf16 exact, 2 terms.
template <int MODE>
__global__ __launch_bounds__(256, 2) void k_gemm4(const void* __restrict__ Av,
                                                  const short* __restrict__ Bp,
                                                  unsigned short* __restrict__ C,
                                                  int M) {
    constexpr int KA = (MODE == 1) ? D_IN : D_HID;
    constexpr int NCH = KA / 32;
    __shared__ short Bs[2][16384];  // 2 x 32 KB

    int t = threadIdx.x;
    int lane = t & 63, w = t >> 6;
    int ln = lane & 15, q = lane >> 4;
    int bm = blockIdx.x * 64;

    // per-strip clamped row base
    const char* Abase[4];
    #pragma unroll
    for (int s = 0; s < 4; ++s) {
        int rr = bm + s * 16 + ln;
        rr = (rr < M) ? rr : (M - 1);
        Abase[s] = (const char*)Av + (size_t)rr * KA * ((MODE == 1) ? 4 : 2);
    }

    f32x4 acc[4][4];
    #pragma unroll
    for (int s = 0; s < 4; ++s)
        #pragma unroll
        for (int tt = 0; tt < 4; ++tt) acc[s][tt] = (f32x4){0.f, 0.f, 0.f, 0.f};

    auto stage = [&](int c, int pb) {
        #pragma unroll
        for (int i = 0; i < 8; ++i) {
            int seg = i * 4 + w;
            gload_lds16(Bp + (size_t)c * 16384 + seg * 512 + lane * 8,
                        &Bs[pb][seg * 512]);
        }
    };

    stage(0, 0);
    __syncthreads();

    for (int c = 0; c < NCH; ++c) {
        int pb = c & 1;
        if (c + 1 < NCH) stage(c + 1, pb ^ 1);

        // A fragments for this chunk
        short8 a_hi[4], a_lo[4];
        #pragma unroll
        for (int s = 0; s < 4; ++s) {
            if (MODE == 1) {
                const float* Af = (const float*)(Abase[s]) + c * 32 + q * 8;
                f32x4 v0 = *(const f32x4*)Af;
                f32x4 v1 = *(const f32x4*)(Af + 4);
                float vv[8] = {v0[0], v0[1], v0[2], v0[3], v1[0], v1[1], v1[2], v1[3]};
                #pragma unroll
                for (int j = 0; j < 8; ++j) {
                    unsigned short h = f2b(vv[j]);
                    a_hi[s][j] = (short)h;
                    a_lo[s][j] = (short)f2b(vv[j] - b2f(h));
                }
            } else {
                const unsigned short* Ab = (const unsigned short*)(Abase[s]) + c * 32 + q * 8;
                a_hi[s] = *(const short8*)Ab;
            }
        }

        #pragma unroll
        for (int tt = 0; tt < 4; ++tt) {
            int T = w * 4 + tt;
            const short* bp = &Bs[pb][(size_t)(T * 4 + q) * 128 + ln * 8];
            short8 bh = *(const short8*)bp;
            short8 bl = *(const short8*)(bp + 8192);
            #pragma unroll
            for (int s = 0; s < 4; ++s) {
                acc[s][tt] = __builtin_amdgcn_mfma_f32_16x16x32_bf16(a_hi[s], bh, acc[s][tt], 0, 0, 0);
                if (MODE == 1)
                    acc[s][tt] = __builtin_amdgcn_mfma_f32_16x16x32_bf16(a_lo[s], bh, acc[s][tt], 0, 0, 0);
                acc[s][tt] = __builtin_amdgcn_mfma_f32_16x16x32_bf16(
                    (MODE == 1) ? a_hi[s] : a_hi[s], bl, acc[s][tt], 0, 0, 0);
            }
        }
        __syncthreads();
    }

    // C/D: row = bm + s*16 + q*4 + r, col = w*64 + tt*16 + ln
    #pragma unroll
    for (int s = 0; s < 4; ++s)
        #pragma unroll
        for (int tt = 0; tt < 4; ++tt)
            #pragma unroll
            for (int r = 0; r < 4; ++r) {
                int row = bm + s * 16 + q * 4 + r;
                if (row < M)
                    C[(size_t)row * 256 + w * 64 + tt * 16 + ln] = f2b(acc[s][tt][r]);
            }
}

// ---------------- aggregation: one wave per dst row, bf16 gather ----------------
template <int RELU, int OUTBF>
__global__ __launch_bounds__(256) void k_agg(const unsigned short* __restrict__ hin,
                                             void* __restrict__ hout,
                                             const int* __restrict__ row_ptr,
                                             const int* __restrict__ csr_src,
                                             const float* __restrict__ dinv,
                                             const float* __restrict__ bias, int N) {
    int w = threadIdx.x >> 6;
    int lane = threadIdx.x & 63;
    int row = blockIdx.x * 4 + w;
    if (row >= N) return;
    int c4 = lane * 4;
    int s = row_ptr[row], e = row_ptr[row + 1];
    float a0 = 0.f, a1 = 0.f, a2 = 0.f, a3 = 0.f;
    int j = s;
    for (; j + 4 <= e; j += 4) {
        int u0 = csr_src[j], u1 = csr_src[j + 1], u2 = csr_src[j + 2], u3 = csr_src[j + 3];
        float d0 = dinv[u0], d1 = dinv[u1], d2 = dinv[u2], d3 = dinv[u3];
        ushort4 v0 = *(const ushort4*)&hin[(size_t)u0 * 256 + c4];
        ushort4 v1 = *(const ushort4*)&hin[(size_t)u1 * 256 + c4];
        ushort4 v2 = *(const ushort4*)&hin[(size_t)u2 * 256 + c4];
        ushort4 v3 = *(const ushort4*)&hin[(size_t)u3 * 256 + c4];
        a0 += d0 * b2f(v0.x) + d1 * b2f(v1.x) + d2 * b2f(v2.x) + d3 * b2f(v3.x);
        a1 += d0 * b2f(v0.y) + d1 * b2f(v1.y) + d2 * b2f(v2.y) + d3 * b2f(v3.y);
        a2 += d0 * b2f(v0.z) + d1 * b2f(v1.z) + d2 * b2f(v2.z) + d3 * b2f(v3.z);
        a3 += d0 * b2f(v0.w) + d1 * b2f(v1.w) + d2 * b2f(v2.w) + d3 * b2f(v3.w);
    }
    for (; j < e; ++j) {
        int u = csr_src[j];
        float d = dinv[u];
        ushort4 v = *(const ushort4*)&hin[(size_t)u * 256 + c4];
        a0 += d * b2f(v.x); a1 += d * b2f(v.y); a2 += d * b2f(v.z); a3 += d * b2f(v.w);
    }
    float di = dinv[row];
    float dii = di * di;
    ushort4 vs = *(const ushort4*)&hin[(size_t)row * 256 + c4];
    float4 bb = *(const float4*)&bias[c4];
    a0 = a0 * di + dii * b2f(vs.x) + bb.x;
    a1 = a1 * di + dii * b2f(vs.y) + bb.y;
    a2 = a2 * di + dii * b2f(vs.z) + bb.z;
    a3 = a3 * di + dii * b2f(vs.w) + bb.w;
    if (RELU) {
        a0 = fmaxf(a0, 0.f); a1 = fmaxf(a1, 0.f);
        a2 = fmaxf(a2, 0.f); a3 = fmaxf(a3, 0.f);
    }
    if (OUTBF) {
        ushort4 o; o.x = f2b(a0); o.y = f2b(a1); o.z = f2b(a2); o.w = f2b(a3);
        *(ushort4*)((unsigned short*)hout + (size_t)row * 256 + c4) = o;
    } else {
        *(float4*)((float*)hout + (size_t)row * 256 + c4) = make_float4(a0, a1, a2, a3);
    }
}

// ---------------- pool ----------------
__global__ __launch_bounds__(256) void k_pool(const float* __restrict__ h,
                                              const int* __restrict__ cnt,
                                              const int* __restrict__ offg,
                                              float* __restrict__ g) {
    int gi = blockIdx.x, slice = blockIdx.y;
    int c = threadIdx.x;
    int start = offg[gi], n = cnt[gi];
    int per = (n + (int)gridDim.y - 1) / (int)gridDim.y;
    int r0 = slice * per;
    int r1 = min(n, r0 + per);
    float acc = 0.f;
    for (int r = r0; r < r1; ++r) acc += h[(size_t)(start + r) * D_HID + c];
    if (r1 > r0) atomicAdd(&g[gi * D_HID + c], acc);
}

// ---------------- head ----------------
__global__ __launch_bounds__(256) void k_final(const float* __restrict__ g,
                                               const int* __restrict__ cnt,
                                               const float* __restrict__ Wl,
                                               const float* __restrict__ bl,
                                               float* __restrict__ out) {
    __shared__ float gs[D_HID];
    int t = threadIdx.x;
    int gi = blockIdx.y;
    int c = blockIdx.x * 256 + t;
    float inv = 1.0f / (float)max(cnt[gi], 1);
    gs[t] = g[gi * D_HID + t] * inv;
    __syncthreads();
    float acc = bl[c];
    #pragma unroll 8
    for (int k = 0; k < D_HID; ++k) acc = fmaf(gs[k], Wl[(size_t)k * D_IN + c], acc);
    out[(size_t)gi * D_IN + c] = acc;
}

// ---------------- launch ----------------

extern "C" void kernel_launch(void* const* d_in, const int* in_sizes, int n_in,
                              void* d_out, int out_size, void* d_ws, size_t ws_size,
                              hipStream_t stream) {
    const float* x     = (const float*)d_in[0];
    const int*   ei    = (const int*)d_in[1];
    const int*   batch = (const int*)d_in[2];
    const float* W1 = (const float*)d_in[3];
    const float* b1 = (const float*)d_in[4];
    const float* W2 = (const float*)d_in[5];
    const float* b2 = (const float*)d_in[6];
    const float* W3 = (const float*)d_in[7];
    const float* b3 = (const float*)d_in[8];
    const float* Wl = (const float*)d_in[9];
    const float* bl = (const float*)d_in[10];
    float* out = (float*)d_out;

    int N = in_sizes[2];
    int E = in_sizes[1] / 2;
    int G = out_size / D_IN;
    const int* srcp = ei;
    const int* dstp = ei + E;

    char* ws = (char*)d_ws;
    size_t o = 0;
    auto alloc = [&](size_t bytes) -> char* {
        char* p = ws + o;
        o += (bytes + 255) & ~(size_t)255;
        return p;
    };
    int*   deg     = (int*)alloc((size_t)N * 4);
    int*   wptr    = (int*)alloc((size_t)N * 4);
    int*   row_ptr = (int*)alloc((size_t)(N + 1) * 4);
    int*   cnt     = (int*)alloc((size_t)G * 4);
    int*   offg    = (int*)alloc((size_t)G * 4);
    int*   csr_src = (int*)alloc((size_t)E * 4);
    float* dinv    = (float*)alloc((size_t)N * 4);
    float* gbuf    = (float*)alloc((size_t)G * D_HID * 4);
    unsigned short* hG  = (unsigned short*)alloc((size_t)N * D_HID * 2); // GEMM out (bf16)
    unsigned short* hA2 = (unsigned short*)alloc((size_t)N * D_HID * 2); // agg out L1/L2 (bf16)
    float* hF      = (float*)alloc((size_t)N * D_HID * 4);               // agg out L3 (fp32)
    short* Bp1     = (short*)alloc((size_t)(D_IN / 32) * 16384 * 2);
    short* Bp2     = (short*)alloc((size_t)(D_HID / 32) * 16384 * 2);
    short* Bp3     = (short*)alloc((size_t)(D_HID / 32) * 16384 * 2);

    hipMemsetAsync(deg, 0, (size_t)N * 4, stream);
    hipMemsetAsync(wptr, 0, (size_t)N * 4, stream);
    hipMemsetAsync(gbuf, 0, (size_t)G * D_HID * 4, stream);

    int gE = (E + 255) / 256;
    int gN = (N + 255) / 256;

    k_count<<<gE, 256, 0, stream>>>(dstp, deg, E);
    k_dinv<<<gN, 256, 0, stream>>>(deg, dinv, N);
    k_scan<<<1, 1024, 0, stream>>>(deg, row_ptr, N);
    k_fill<<<gE, 256, 0, stream>>>(srcp, dstp, row_ptr, wptr, csr_src, E);
    k_bounds<<<1, 64, 0, stream>>>(batch, cnt, offg, N, G);

    k_prep_B<<<D_IN, 256, 0, stream>>>(W1, Bp1, D_IN);
    k_prep_B<<<D_HID, 256, 0, stream>>>(W2, Bp2, D_HID);
    k_prep_B<<<D_HID, 256, 0, stream>>>(W3, Bp3, D_HID);

    int gemm_grid = (N + 63) / 64;
    int agg_grid = (N + 3) / 4;

    // layer 1 (fp32 A, 3-term fused)
    k_gemm4<1><<<gemm_grid, 256, 0, stream>>>(x, Bp1, hG, N);
    k_agg<1, 1><<<agg_grid, 256, 0, stream>>>(hG, hA2, row_ptr, csr_src, dinv, b1, N);
    // layer 2 (bf16 A exact, 2-term)
    k_gemm4<2><<<gemm_grid, 256, 0, stream>>>(hA2, Bp2, hG, N);
    k_agg<1, 1><<<agg_grid, 256, 0, stream>>>(hG, hA2, row_ptr, csr_src, dinv, b2, N);
    // layer 3
    k_gemm4<2><<<gemm_grid, 256, 0, stream>>>(hA2, Bp3, hG, N);
    k_agg<0, 0><<<agg_grid, 256, 0, stream>>>(hG, hF, row_ptr, csr_src, dinv, b3, N);

    // pool + head
    dim3 pool_grid(G, 8);
    k_pool<<<pool_grid, 256, 0, stream>>>(hF, cnt, offg, gbuf);
    dim3 fin_grid(D_IN / 256, G);
    k_final<<<fin_grid, 256, 0, stream>>>(gbuf, cnt, Wl, bl, out);
}